// Round 4
// baseline (1183.766 us; speedup 1.0000x reference)
//
#include <hip/hip_runtime.h>
#include <cstddef>
#include <cstdint>

// Problem constants (match reference)
#define N_SRC1 1210000
#define N_DST1 110000
#define N_SRC2 110000
#define N_DST2 10000
#define E1 1100000
#define E2 100000
#define IN_DIM 128
#define HID_DIM 256
#define OUT_DIM 128

// ---------------- degree + dst-count accumulation (both layers, one launch) ----------------
__global__ __launch_bounds__(256) void count_both(const int* __restrict__ src1,
                                                  const int* __restrict__ dst1,
                                                  const int* __restrict__ src2,
                                                  const int* __restrict__ dst2,
                                                  float* __restrict__ outdeg1,
                                                  int* __restrict__ cnt1,
                                                  float* __restrict__ outdeg2,
                                                  int* __restrict__ cnt2) {
    int i = blockIdx.x * 256 + threadIdx.x;
    if (i < E1) {
        unsafeAtomicAdd(&outdeg1[src1[i]], 1.0f);
        atomicAdd(&cnt1[dst1[i]], 1);
    } else if (i < E1 + E2) {
        int k = i - E1;
        unsafeAtomicAdd(&outdeg2[src2[k]], 1.0f);
        atomicAdd(&cnt2[dst2[k]], 1);
    }
}

// ---------------- device-wide exclusive scan, 3 phases, both levels per launch ----------------
__global__ __launch_bounds__(1024) void scan_part_both(const int* __restrict__ cnt1,
                                                       int* __restrict__ offs1,
                                                       int* __restrict__ bsum1,
                                                       const int* __restrict__ cnt2,
                                                       int* __restrict__ offs2,
                                                       int* __restrict__ bsum2, int nb1) {
    const int* cnt; int* offs; int* bsum; int n; int lb;
    if ((int)blockIdx.x < nb1) { cnt = cnt1; offs = offs1; bsum = bsum1; n = N_DST1; lb = blockIdx.x; }
    else                       { cnt = cnt2; offs = offs2; bsum = bsum2; n = N_DST2; lb = blockIdx.x - nb1; }
    __shared__ int smem[1024];
    int i = lb * 1024 + threadIdx.x;
    int v = (i < n) ? cnt[i] : 0;
    smem[threadIdx.x] = v;
    __syncthreads();
    #pragma unroll
    for (int off = 1; off < 1024; off <<= 1) {
        int t = (threadIdx.x >= off) ? smem[threadIdx.x - off] : 0;
        __syncthreads();
        smem[threadIdx.x] += t;
        __syncthreads();
    }
    if (i < n) offs[i] = smem[threadIdx.x] - v;      // block-local exclusive
    if (threadIdx.x == 1023) bsum[lb] = smem[1023];
}

__global__ __launch_bounds__(1024) void scan_bsum_both(int* __restrict__ bsum1,
                                                       int* __restrict__ end1, int nb1,
                                                       int* __restrict__ bsum2,
                                                       int* __restrict__ end2, int nb2) {
    int* bsum; int* oend; int nb;
    if (blockIdx.x == 0) { bsum = bsum1; oend = end1; nb = nb1; }
    else                 { bsum = bsum2; oend = end2; nb = nb2; }
    __shared__ int smem[1024];
    int v = ((int)threadIdx.x < nb) ? bsum[threadIdx.x] : 0;
    smem[threadIdx.x] = v;
    __syncthreads();
    #pragma unroll
    for (int off = 1; off < 1024; off <<= 1) {
        int t = (threadIdx.x >= off) ? smem[threadIdx.x - off] : 0;
        __syncthreads();
        smem[threadIdx.x] += t;
        __syncthreads();
    }
    if ((int)threadIdx.x < nb) bsum[threadIdx.x] = smem[threadIdx.x] - v;  // exclusive
    if ((int)threadIdx.x == nb - 1) *oend = smem[threadIdx.x];             // grand total
}

__global__ __launch_bounds__(1024) void scan_add_both(int* __restrict__ offs1,
                                                      int* __restrict__ cursor1,
                                                      const int* __restrict__ bsum1,
                                                      int* __restrict__ offs2,
                                                      int* __restrict__ cursor2,
                                                      const int* __restrict__ bsum2, int nb1) {
    int* offs; int* cursor; const int* bsum; int n; int lb;
    if ((int)blockIdx.x < nb1) { offs = offs1; cursor = cursor1; bsum = bsum1; n = N_DST1; lb = blockIdx.x; }
    else                       { offs = offs2; cursor = cursor2; bsum = bsum2; n = N_DST2; lb = blockIdx.x - nb1; }
    int i = lb * 1024 + threadIdx.x;
    if (i < n) {
        int o = offs[i] + bsum[lb];
        offs[i] = o;
        cursor[i] = o;
    }
}

// ---------------- bucket fill: edge src ids grouped by dst (both layers) ----------------
__global__ __launch_bounds__(256) void fill_both(const int* __restrict__ src1,
                                                 const int* __restrict__ dst1,
                                                 int* __restrict__ cursor1,
                                                 int* __restrict__ elist1,
                                                 const int* __restrict__ src2,
                                                 const int* __restrict__ dst2,
                                                 int* __restrict__ cursor2,
                                                 int* __restrict__ elist2) {
    int i = blockIdx.x * 256 + threadIdx.x;
    if (i < E1) {
        int pos = atomicAdd(&cursor1[dst1[i]], 1);
        elist1[pos] = src1[i];
    } else if (i < E1 + E2) {
        int k = i - E1;
        int pos = atomicAdd(&cursor2[dst2[k]], 1);
        elist2[pos] = src2[k];
    }
}

// ---------------- fused gather1 + GEMM1 + bias + sigmoid gate ----------------
// Each block owns 64 dst rows. Phase 1: wave w gathers rows w*8..w*8+7 directly
// into As (4-deep pipelined edge loop, rsqrt of raw degree inlined — kills the
// separate rsqrt pass and the 112 MB agg1 HBM round-trip). Phase 2: the proven
// 64x256 GEMM. Wave->row mapping identical in both phases (rbase = wid*8).
// LDS 66560 B -> 2 blocks/CU; gather-waves and GEMM-waves of the two blocks
// overlap VMEM vs VALU pipes on each CU.
__global__ __launch_bounds__(512) void gather_gemm1_gate(const float* __restrict__ feat,
                                                         const int* __restrict__ elist,
                                                         const int* __restrict__ offs,
                                                         const float* __restrict__ outdeg,
                                                         const float* __restrict__ W,
                                                         const float* __restrict__ bias,
                                                         const float* __restrict__ attn,
                                                         float* __restrict__ h1, int M) {
    __shared__ float As[64][IN_DIM + 4];
    __shared__ float Bs[32][HID_DIM];
    const int t = threadIdx.x;
    const int row0 = blockIdx.x * 64;
    const int lane = t & 63;
    const int wid = t >> 6;          // 0..7
    const int col = lane;            // *4 -> cols
    const int rbase = wid * 8;

    // ---- phase 1: gather 8 rows per wave into As
    for (int rr = 0; rr < 8; ++rr) {
        int r = rbase + rr;
        int d = row0 + r;
        float2 acc = make_float2(0.f, 0.f);
        if (d < M) {
            int beg = offs[d], end = offs[d + 1];
            int j = beg;
            for (; j + 4 <= end; j += 4) {
                int s0 = elist[j + 0];
                int s1 = elist[j + 1];
                int s2 = elist[j + 2];
                int s3 = elist[j + 3];
                float c0 = rsqrtf(fmaxf(outdeg[s0], 1.f));
                float c1 = rsqrtf(fmaxf(outdeg[s1], 1.f));
                float c2 = rsqrtf(fmaxf(outdeg[s2], 1.f));
                float c3 = rsqrtf(fmaxf(outdeg[s3], 1.f));
                float2 v0 = ((const float2*)(feat + (size_t)s0 * IN_DIM))[lane];
                float2 v1 = ((const float2*)(feat + (size_t)s1 * IN_DIM))[lane];
                float2 v2 = ((const float2*)(feat + (size_t)s2 * IN_DIM))[lane];
                float2 v3 = ((const float2*)(feat + (size_t)s3 * IN_DIM))[lane];
                acc.x += v0.x * c0 + v1.x * c1 + v2.x * c2 + v3.x * c3;
                acc.y += v0.y * c0 + v1.y * c1 + v2.y * c2 + v3.y * c3;
            }
            for (; j < end; ++j) {
                int s = elist[j];
                float sc = rsqrtf(fmaxf(outdeg[s], 1.f));
                float2 v = ((const float2*)(feat + (size_t)s * IN_DIM))[lane];
                acc.x += v.x * sc;
                acc.y += v.y * sc;
            }
            float rin = rsqrtf(fmaxf((float)(end - beg), 1.f));
            acc.x *= rin; acc.y *= rin;
        }
        *(float2*)&As[r][lane * 2] = acc;   // row stride 528 B (8B-aligned), 2-way bank alias = free
    }

    // ---- phase 2: GEMM (first __syncthreads covers the As writes)
    float4 acc[8];
    #pragma unroll
    for (int rr = 0; rr < 8; ++rr) acc[rr] = make_float4(0.f, 0.f, 0.f, 0.f);

    for (int kc = 0; kc < 4; ++kc) {   // K chunks of 32
        __syncthreads();
        #pragma unroll
        for (int i = 0; i < 4; ++i) {
            int idx = t + i * 512;      // 0..2047 float4 slots (32x64)
            int kk = idx >> 6, c4 = idx & 63;
            *(float4*)&Bs[kk][c4 * 4] = ((const float4*)(W + (size_t)(kc * 32 + kk) * HID_DIM))[c4];
        }
        __syncthreads();
        #pragma unroll 2
        for (int k4 = 0; k4 < 8; ++k4) {
            int kk = k4 * 4;
            float4 b0 = *(float4*)&Bs[kk + 0][col * 4];
            float4 b1v = *(float4*)&Bs[kk + 1][col * 4];
            float4 b2v = *(float4*)&Bs[kk + 2][col * 4];
            float4 b3v = *(float4*)&Bs[kk + 3][col * 4];
            int ka = kc * 32 + kk;
            #pragma unroll
            for (int rr = 0; rr < 8; ++rr) {
                float4 a = *(const float4*)&As[rbase + rr][ka];
                acc[rr].x += a.x * b0.x + a.y * b1v.x + a.z * b2v.x + a.w * b3v.x;
                acc[rr].y += a.x * b0.y + a.y * b1v.y + a.z * b2v.y + a.w * b3v.y;
                acc[rr].z += a.x * b0.z + a.y * b1v.z + a.z * b2v.z + a.w * b3v.z;
                acc[rr].w += a.x * b0.w + a.y * b1v.w + a.z * b2v.w + a.w * b3v.w;
            }
        }
    }

    float4 bb = *(const float4*)&bias[col * 4];
    float4 at = *(const float4*)&attn[col * 4];
    #pragma unroll
    for (int rr = 0; rr < 8; ++rr) {
        int row = row0 + rbase + rr;
        float4 v = acc[rr];
        v.x += bb.x; v.y += bb.y; v.z += bb.z; v.w += bb.w;
        float p = v.x * at.x + v.y * at.y + v.z * at.z + v.w * at.w;
        p += __shfl_down(p, 32);
        p += __shfl_down(p, 16);
        p += __shfl_down(p, 8);
        p += __shfl_down(p, 4);
        p += __shfl_down(p, 2);
        p += __shfl_down(p, 1);
        p = __shfl(p, 0);
        float alpha = 1.f / (1.f + expf(-p));
        v.x *= alpha; v.y *= alpha; v.z *= alpha; v.w *= alpha;
        if (row < M) *(float4*)&h1[(size_t)row * HID_DIM + col * 4] = v;
    }
}

// ---------------- layer-2 gather: one wave (64 lanes x float4) per dst row ----------------
// rsqrt of raw degree inlined (rsqrt pass eliminated).
__global__ __launch_bounds__(256) void gather2_kernel(const float* __restrict__ h1,
                                                      const int* __restrict__ elist,
                                                      const int* __restrict__ offs,
                                                      const float* __restrict__ outdeg,
                                                      float* __restrict__ agg, int n_dst) {
    int d = blockIdx.x * 4 + (threadIdx.x >> 6);
    if (d >= n_dst) return;
    int lane = threadIdx.x & 63;
    int beg = offs[d], end = offs[d + 1];
    float4 acc = make_float4(0.f, 0.f, 0.f, 0.f);
    int j = beg;
    for (; j + 4 <= end; j += 4) {
        int s0 = elist[j + 0];
        int s1 = elist[j + 1];
        int s2 = elist[j + 2];
        int s3 = elist[j + 3];
        float c0 = rsqrtf(fmaxf(outdeg[s0], 1.f));
        float c1 = rsqrtf(fmaxf(outdeg[s1], 1.f));
        float c2 = rsqrtf(fmaxf(outdeg[s2], 1.f));
        float c3 = rsqrtf(fmaxf(outdeg[s3], 1.f));
        float4 v0 = ((const float4*)(h1 + (size_t)s0 * HID_DIM))[lane];
        float4 v1 = ((const float4*)(h1 + (size_t)s1 * HID_DIM))[lane];
        float4 v2 = ((const float4*)(h1 + (size_t)s2 * HID_DIM))[lane];
        float4 v3 = ((const float4*)(h1 + (size_t)s3 * HID_DIM))[lane];
        acc.x += v0.x * c0 + v1.x * c1 + v2.x * c2 + v3.x * c3;
        acc.y += v0.y * c0 + v1.y * c1 + v2.y * c2 + v3.y * c3;
        acc.z += v0.z * c0 + v1.z * c1 + v2.z * c2 + v3.z * c3;
        acc.w += v0.w * c0 + v1.w * c1 + v2.w * c2 + v3.w * c3;
    }
    for (; j < end; ++j) {
        int s = elist[j];
        float sc = rsqrtf(fmaxf(outdeg[s], 1.f));
        float4 v = ((const float4*)(h1 + (size_t)s * HID_DIM))[lane];
        acc.x += v.x * sc;
        acc.y += v.y * sc;
        acc.z += v.z * sc;
        acc.w += v.w * sc;
    }
    float rin = rsqrtf(fmaxf((float)(end - beg), 1.f));
    acc.x *= rin; acc.y *= rin; acc.z *= rin; acc.w *= rin;
    ((float4*)(agg + (size_t)d * HID_DIM))[lane] = acc;
}

// ---------------- GEMM2 + bias + sigmoid gate -> outputs ----------------
__global__ __launch_bounds__(256) void gemm2_gate(const float* __restrict__ agg,
                                                  const float* __restrict__ W,
                                                  const float* __restrict__ bias,
                                                  const float* __restrict__ attn,
                                                  float* __restrict__ out_h,
                                                  float* __restrict__ out_alpha, int M) {
    __shared__ float As[32][HID_DIM + 4];
    __shared__ float Bs[32][OUT_DIM];
    const int t = threadIdx.x;
    const int row0 = blockIdx.x * 32;
    const int col = t & 63;         // *2 -> cols
    const int rbase = (t >> 6) * 8; // wave-uniform

    #pragma unroll
    for (int i = 0; i < 8; ++i) {
        int idx = t + i * 256;       // 0..2047 float4 slots (32x64)
        int r = idx >> 6, c4 = idx & 63;
        int row = row0 + r;
        float4 v = make_float4(0.f, 0.f, 0.f, 0.f);
        if (row < M) v = ((const float4*)(agg + (size_t)row * HID_DIM))[c4];
        *(float4*)&As[r][c4 * 4] = v;
    }

    float2 acc[8];
    #pragma unroll
    for (int rr = 0; rr < 8; ++rr) acc[rr] = make_float2(0.f, 0.f);

    for (int kc = 0; kc < 8; ++kc) {   // K=256, chunks of 32
        __syncthreads();
        #pragma unroll
        for (int i = 0; i < 4; ++i) {
            int idx = t + i * 256;      // 0..1023 float4 slots (32x32)
            int kk = idx >> 5, c4 = idx & 31;
            *(float4*)&Bs[kk][c4 * 4] = ((const float4*)(W + (size_t)(kc * 32 + kk) * OUT_DIM))[c4];
        }
        __syncthreads();
        #pragma unroll
        for (int k4 = 0; k4 < 8; ++k4) {
            int kk = k4 * 4;
            float2 b0 = *(float2*)&Bs[kk + 0][col * 2];
            float2 b1v = *(float2*)&Bs[kk + 1][col * 2];
            float2 b2v = *(float2*)&Bs[kk + 2][col * 2];
            float2 b3v = *(float2*)&Bs[kk + 3][col * 2];
            int ka = kc * 32 + kk;
            #pragma unroll
            for (int rr = 0; rr < 8; ++rr) {
                float4 a = *(const float4*)&As[rbase + rr][ka];
                acc[rr].x += a.x * b0.x + a.y * b1v.x + a.z * b2v.x + a.w * b3v.x;
                acc[rr].y += a.x * b0.y + a.y * b1v.y + a.z * b2v.y + a.w * b3v.y;
            }
        }
    }

    float2 bb = *(const float2*)&bias[col * 2];
    float2 at = *(const float2*)&attn[col * 2];
    #pragma unroll
    for (int rr = 0; rr < 8; ++rr) {
        int row = row0 + rbase + rr;
        float2 v = acc[rr];
        v.x += bb.x; v.y += bb.y;
        float p = v.x * at.x + v.y * at.y;
        p += __shfl_down(p, 32);
        p += __shfl_down(p, 16);
        p += __shfl_down(p, 8);
        p += __shfl_down(p, 4);
        p += __shfl_down(p, 2);
        p += __shfl_down(p, 1);
        p = __shfl(p, 0);
        float alpha = 1.f / (1.f + expf(-p));
        v.x *= alpha; v.y *= alpha;
        if (row < M) {
            *(float2*)&out_h[(size_t)row * OUT_DIM + col * 2] = v;
            if (col == 0) out_alpha[row] = alpha;
        }
    }
}

extern "C" void kernel_launch(void* const* d_in, const int* in_sizes, int n_in,
                              void* d_out, int out_size, void* d_ws, size_t ws_size,
                              hipStream_t stream) {
    const float* feat  = (const float*)d_in[0];
    const float* W1    = (const float*)d_in[1];
    const float* b1    = (const float*)d_in[2];
    const float* attn1 = (const float*)d_in[3];
    const float* W2    = (const float*)d_in[4];
    const float* b2    = (const float*)d_in[5];
    const float* attn2 = (const float*)d_in[6];
    const int* src1 = (const int*)d_in[7];
    const int* dst1 = (const int*)d_in[8];
    const int* src2 = (const int*)d_in[9];
    const int* dst2 = (const int*)d_in[10];
    float* out = (float*)d_out;

    // workspace layout
    float* ws = (float*)d_ws;
    float* outdeg1 = ws;                                   // N_SRC1 (zeroed, raw counts)
    float* outdeg2 = outdeg1 + N_SRC1;                     // N_SRC2 (zeroed, raw counts)
    int*   cnt1    = (int*)(outdeg2 + N_SRC2);             // N_DST1 (zeroed)
    int*   cnt2    = cnt1 + N_DST1;                        // N_DST2 (zeroed)
    int*   offs1   = cnt2 + N_DST2;                        // N_DST1+1
    int*   cursor1 = offs1 + N_DST1 + 1;                   // N_DST1
    int*   offs2   = cursor1 + N_DST1;                     // N_DST2+1
    int*   cursor2 = offs2 + N_DST2 + 1;                   // N_DST2
    int*   elist1  = cursor2 + N_DST2;                     // E1
    int*   elist2  = elist1 + E1;                          // E2
    float* agg2    = (float*)(elist2 + E2);                // N_DST2*HID_DIM
    float* h1      = agg2 + (size_t)N_DST2 * HID_DIM;      // N_DST1*HID_DIM
    int*   bsum1   = (int*)(h1 + (size_t)N_DST1 * HID_DIM); // 128 block sums
    int*   bsum2   = bsum1 + 128;                          // 16 block sums

    // zero only the atomic-accumulated arrays (outdeg1, outdeg2, cnt1, cnt2 contiguous)
    const size_t zero_bytes = ((size_t)N_SRC1 + N_SRC2 + N_DST1 + N_DST2) * 4;
    hipMemsetAsync(d_ws, 0, zero_bytes, stream);

    count_both<<<(E1 + E2 + 255) / 256, 256, 0, stream>>>(src1, dst1, src2, dst2,
                                                          outdeg1, cnt1, outdeg2, cnt2);

    const int nb1 = (N_DST1 + 1023) / 1024;   // 108
    const int nb2 = (N_DST2 + 1023) / 1024;   // 10
    scan_part_both<<<nb1 + nb2, 1024, 0, stream>>>(cnt1, offs1, bsum1, cnt2, offs2, bsum2, nb1);
    scan_bsum_both<<<2, 1024, 0, stream>>>(bsum1, offs1 + N_DST1, nb1, bsum2, offs2 + N_DST2, nb2);
    scan_add_both<<<nb1 + nb2, 1024, 0, stream>>>(offs1, cursor1, bsum1, offs2, cursor2, bsum2, nb1);

    fill_both<<<(E1 + E2 + 255) / 256, 256, 0, stream>>>(src1, dst1, cursor1, elist1,
                                                         src2, dst2, cursor2, elist2);

    gather_gemm1_gate<<<(N_DST1 + 63) / 64, 512, 0, stream>>>(feat, elist1, offs1, outdeg1,
                                                              W1, b1, attn1, h1, N_DST1);
    gather2_kernel<<<(N_DST2 + 3) / 4, 256, 0, stream>>>(h1, elist2, offs2, outdeg2, agg2, N_DST2);
    gemm2_gate<<<(N_DST2 + 31) / 32, 256, 0, stream>>>(agg2, W2, b2, attn2,
                                                       out, out + (size_t)N_DST2 * OUT_DIM, N_DST2);
}